// Round 3
// baseline (391.538 us; speedup 1.0000x reference)
//
#include <hip/hip_runtime.h>
#include <math.h>

#define B_Q 1024
#define L_SEQ 128
#define D_EMB 256
#define NLAB 131072
#define LBL_ROWS 8192
#define NEG_ROWS 2048
#define W_ROWS 10240
#define CROW 320   // compact row: 64 poly + 256 prf
#define LST 82     // k_score LDS row stride
#define RPB 32     // wproj rows per block
#define SXS 258    // sx row stride (<=2-way LDS conflicts, float2-aligned)
#define SLOT_EMPTY 0x7FFFFFFF

__device__ __forceinline__ float wave_sum(float v) {
#pragma unroll
  for (int off = 32; off > 0; off >>= 1) v += __shfl_xor(v, off, 64);
  return v;
}

// sx: 256 per-head-normalized dims in LDS. t in [0,256). One compact row out.
__device__ __forceinline__ void slay_tail(const float* __restrict__ sx, int t,
                                          const float* __restrict__ anchT,
                                          const float* __restrict__ omega,
                                          float* __restrict__ outrow) {
  if (t < 64) {
    const int h = t >> 4, p = t & 15;
    const float* x = sx + h * 64;
    float d = 0.f;
#pragma unroll
    for (int dd = 0; dd < 64; dd++) d = fmaf(x[dd], anchT[dd * 16 + p], d);
    d = fminf(fmaxf(d, -1.0f), 1.0f);
    outrow[h * 16 + p] = d * d * 0.25f;
  }
  {
    const int r = t >> 7;
    const int h = (t >> 5) & 3;
    const float* x = sx + h * 64;
    const float* om = omega + (size_t)(t >> 5) * 2048 + (t & 31);
    float d = 0.f;
#pragma unroll
    for (int dd = 0; dd < 64; dd++) d = fmaf(x[dd], om[dd * 32], d);
    const float proj = d * 0.125f;
    const float s = r ? 1.70710592763316f : 0.29289307236691f;
    const float w = r ? 0.07322326809171f : 0.42677648190829f;
    float arg = proj * sqrtf(2.0f * s) - s;
    arg = fminf(fmaxf(arg, -20.0f), 20.0f);
    outrow[64 + t] = expf(arg) * (sqrtf(w) / sqrtf(32.000001f));
  }
}

// block 0: anchors. 1..256: zero negparts. 257..264: zero hist.
// 265..776: slotmap = SLOT_EMPTY.
__global__ __launch_bounds__(256) void k_prep(const float* __restrict__ anchors,
                                              float* __restrict__ anchT,
                                              float* __restrict__ negparts,
                                              int* __restrict__ hist,
                                              int* __restrict__ slotmap) {
  const int t = threadIdx.x, bx = blockIdx.x;
  if (bx == 0) {
    if (t < 64) {
      for (int p = 0; p < 16; p++) {
        const float v = anchors[p * 64 + t];
        const float n = sqrtf(wave_sum(v * v));
        anchT[t * 16 + p] = v / n;
      }
    }
  } else if (bx <= 256) {
    negparts[(bx - 1) * 256 + t] = 0.f;
  } else if (bx <= 264) {
    hist[(bx - 257) * 256 + t] = 0;
  } else {
    slotmap[(bx - 265) * 256 + t] = SLOT_EMPTY;
  }
}

// compute j per row, histogram over j>>6 (2048 buckets)
__global__ __launch_bounds__(256) void k_mark(const int* __restrict__ labels,
                                              const int* __restrict__ negidx,
                                              int* __restrict__ jidx,
                                              int* __restrict__ hist) {
  const int i = blockIdx.x * 256 + threadIdx.x;
  if (i >= W_ROWS) return;
  int j;
  if (i < LBL_ROWS) { j = labels[i]; if (j < 0) j = 0; }
  else               { j = negidx[i - LBL_ROWS]; }
  jidx[i] = j;
  atomicAdd(&hist[j >> 6], 1);
}

// single-block exclusive scan of 2048-entry hist
__global__ __launch_bounds__(256) void k_scan(int* __restrict__ hist) {
  __shared__ int s[256];
  const int t = threadIdx.x;
  int v[8]; int sum = 0;
#pragma unroll
  for (int e = 0; e < 8; e++) { v[e] = hist[t * 8 + e]; sum += v[e]; }
  s[t] = sum; __syncthreads();
  for (int off = 1; off < 256; off <<= 1) {
    const int x = s[t];
    const int y = (t >= off) ? s[t - off] : 0;
    __syncthreads();
    s[t] = x + y;
    __syncthreads();
  }
  int run = s[t] - sum;
#pragma unroll
  for (int e = 0; e < 8; e++) { hist[t * 8 + e] = run; run += v[e]; }
}

// scatter row ids into sorted-j order; record canonical (min) slot per j
__global__ __launch_bounds__(256) void k_scatter(const int* __restrict__ jidx,
                                                 int* __restrict__ hist,
                                                 int* __restrict__ sorted,
                                                 int* __restrict__ slotmap) {
  const int i = blockIdx.x * 256 + threadIdx.x;
  if (i >= W_ROWS) return;
  const int j = jidx[i];
  const int pos = atomicAdd(&hist[j >> 6], 1);
  sorted[pos] = i;
  atomicMin(&slotmap[j], pos);
}

// Fused dense-stream gather + query.
// blocks [0,2048): stream kern (d = bx>>3, col-chunk = bx&7 -> chunk==XCD,
//   slotmap slice stays L2-resident per XCD). Coalesced float4 reads at ~peak BW;
//   needed columns written to compact wgath[d][slot].
// blocks [2048,3072): query path (independent).
__global__ __launch_bounds__(256) void k_gather(const float* __restrict__ kern,
                                                const int* __restrict__ slotmap,
                                                float* __restrict__ wgath,
                                                const int* __restrict__ indices,
                                                const float* __restrict__ mask,
                                                const float* __restrict__ embed,
                                                const float* __restrict__ anchT,
                                                const float* __restrict__ omega,
                                                float* __restrict__ qcomp) {
  const int tid = threadIdx.x;
  if (blockIdx.x < 2048) {
    const int d = blockIdx.x >> 3, chunk = blockIdx.x & 7;
    const float4* kb = (const float4*)(kern + ((size_t)d << 17)) + chunk * 4096;
    const int4* sm = (const int4*)slotmap + chunk * 4096;
    float* wg = wgath + (size_t)d * W_ROWS;
#pragma unroll 4
    for (int it = 0; it < 16; it++) {
      const int idx = it * 256 + tid;
      const float4 v = kb[idx];
      const int4 s = sm[idx];
      if (s.x < W_ROWS) wg[s.x] = v.x;
      if (s.y < W_ROWS) wg[s.y] = v.y;
      if (s.z < W_ROWS) wg[s.z] = v.z;
      if (s.w < W_ROWS) wg[s.w] = v.w;
    }
  } else {
    // ---------------- query path ----------------
    __shared__ __align__(16) float smem[1552];
    const int b = blockIdx.x - 2048, t = tid;
    const int wv = t >> 6, ln = t & 63;
    int* sidx = (int*)smem;                 // 128
    float* smask = smem + 128;              // 128
    float4* spart = (float4*)(smem + 256);  // 256 float4
    float* smsum = smem + 1280;             // 4
    float* sx = smem + 1296;                // 256
    if (t < L_SEQ) { sidx[t] = indices[b * L_SEQ + t]; smask[t] = mask[b * L_SEQ + t]; }
    __syncthreads();
    float4 acc = {0.f, 0.f, 0.f, 0.f};
    float msum = 0.f;
#pragma unroll 8
    for (int l = wv * 32; l < wv * 32 + 32; l++) {
      const float m = smask[l];
      msum += m;
      const float4 e = *(const float4*)(embed + (size_t)sidx[l] * D_EMB + ln * 4);
      acc.x = fmaf(e.x, m, acc.x); acc.y = fmaf(e.y, m, acc.y);
      acc.z = fmaf(e.z, m, acc.z); acc.w = fmaf(e.w, m, acc.w);
    }
    spart[wv * 64 + ln] = acc;
    if (ln == 0) smsum[wv] = msum;
    __syncthreads();
    const float* spf = (const float*)spart;
    float q = spf[t] + spf[256 + t] + spf[512 + t] + spf[768 + t];
    const float mt = smsum[0] + smsum[1] + smsum[2] + smsum[3];
    q /= fmaxf(mt, 1.0f);
    const float ss = wave_sum(q * q);  // wave == head
    sx[t] = q / fmaxf(sqrtf(ss), 1e-4f);
    __syncthreads();
    slay_tail(sx, t, anchT, omega, qcomp + (size_t)b * CROW);
  }
}

// W projections from compact wgath: 32 sorted rows/block, coalesced band reads.
// Normalization folded into projections (linear in x).
__global__ __launch_bounds__(256) void k_wproj(const int* __restrict__ sorted,
                                               const int* __restrict__ jidx,
                                               const int* __restrict__ slotmap,
                                               const float* __restrict__ wgath,
                                               const float* __restrict__ anchT,
                                               const float* __restrict__ omega,
                                               float* __restrict__ wcomp) {
  __shared__ __align__(16) float smem[9536];
  int* sj = (int*)smem;              // 32
  int* ssid = (int*)smem + 32;       // 32
  int* sslot = (int*)smem + 64;      // 32
  float* rnorm = smem + 96;          // 128 (reciprocal norms, [row][head])
  float* sq = smem + 224;            // 32*33 = 1056 (ssq partials, padded)
  float* sx = smem + 1280;           // 32*258 = 8256
  const int tid = threadIdx.x;
  const int lb = blockIdx.x;         // [0, 320)
  // XCD-contiguous remap: matches writer XCD (chunk == j>>14 ~ band/1280)
  const int cb = (lb & 7) * 40 + (lb >> 3);
  const int i0 = cb * RPB;

  if (tid < RPB) {
    const int sid = sorted[i0 + tid];
    ssid[tid] = sid;
    const int j = jidx[sid];
    sj[tid] = j;
    sslot[tid] = slotmap[j];
  }
  __syncthreads();

  // coalesced band gather: thread = (dloc, row); dim = it*8+dloc
  {
    const int row = tid & 31, dloc = tid >> 5;
    const float* wg = wgath + sslot[row];
    float ssq[4] = {0.f, 0.f, 0.f, 0.f};
#pragma unroll
    for (int it = 0; it < 32; it++) {
      const float v = wg[(size_t)(it * 8 + dloc) * W_ROWS];
      sx[row * SXS + it * 8 + dloc] = v;
      ssq[it >> 3] = fmaf(v, v, ssq[it >> 3]);
    }
#pragma unroll
    for (int h = 0; h < 4; h++) sq[row * 33 + dloc * 4 + h] = ssq[h];
  }
  __syncthreads();
  if (tid < 128) {
    const int r2 = tid >> 2, h = tid & 3;
    float s = 0.f;
#pragma unroll
    for (int dl = 0; dl < 8; dl++) s += sq[r2 * 33 + dl * 4 + h];
    rnorm[r2 * 4 + h] = 1.0f / fmaxf(sqrtf(s), 1e-4f);
  }
  __syncthreads();

  // prf: thread = (r,h,m); omega loaded once per block for 32 rows.
  {
    const int hh = (tid >> 5) & 3, r = tid >> 7;
    const float* om = omega + (size_t)(tid >> 5) * 2048 + (tid & 31);
    const float s = r ? 1.70710592763316f : 0.29289307236691f;
    const float w = r ? 0.07322326809171f : 0.42677648190829f;
    const float sc = sqrtf(2.0f * s);
    const float outs = sqrtf(w) / sqrtf(32.000001f);
#pragma unroll
    for (int half = 0; half < 2; half++) {
      float acc[16];
#pragma unroll
      for (int rq = 0; rq < 16; rq++) acc[rq] = 0.f;
#pragma unroll
      for (int dd = 0; dd < 64; dd += 2) {
        const float o0 = om[dd * 32], o1 = om[dd * 32 + 32];
#pragma unroll
        for (int rq = 0; rq < 16; rq++) {
          const float2 xv = *(const float2*)(sx + (half * 16 + rq) * SXS + hh * 64 + dd);
          acc[rq] = fmaf(xv.x, o0, fmaf(xv.y, o1, acc[rq]));
        }
      }
#pragma unroll
      for (int rq = 0; rq < 16; rq++) {
        const int row = half * 16 + rq;
        float arg = acc[rq] * 0.125f * rnorm[row * 4 + hh] * sc - s;
        arg = fminf(fmaxf(arg, -20.0f), 20.0f);
        wcomp[(size_t)ssid[row] * CROW + 64 + tid] = expf(arg) * outs;
      }
    }
  }

  // poly: thread = (hp, rowgroup); 8 rows each, 2 at a time.
  {
    const int hp = tid & 63, rp = tid >> 6;
    const int h = hp >> 4, p = hp & 15;
#pragma unroll
    for (int pr = 0; pr < 4; pr++) {
      const int r0 = rp * 8 + pr * 2;
      const float* x0 = sx + r0 * SXS + h * 64;
      const float* x1 = x0 + SXS;
      float d0 = 0.f, d1 = 0.f;
#pragma unroll
      for (int dd = 0; dd < 64; dd++) {
        const float a = anchT[dd * 16 + p];
        d0 = fmaf(x0[dd], a, d0);
        d1 = fmaf(x1[dd], a, d1);
      }
      d0 *= rnorm[r0 * 4 + h];
      d1 *= rnorm[(r0 + 1) * 4 + h];
      d0 = fminf(fmaxf(d0, -1.0f), 1.0f);
      d1 = fminf(fmaxf(d1, -1.0f), 1.0f);
      wcomp[(size_t)ssid[r0] * CROW + h * 16 + p]     = d0 * d0 * 0.25f;
      wcomp[(size_t)ssid[r0 + 1] * CROW + h * 16 + p] = d1 * d1 * 0.25f;
    }
  }
}

// Fused neg + pos: blocks [0,4096) neg tiles (qb,wb,h), [4096,4352) pos.
__global__ __launch_bounds__(128) void k_score(const float* __restrict__ qcomp,
                                               const float* __restrict__ wcomp,
                                               float* __restrict__ negparts,
                                               float* __restrict__ pos) {
  __shared__ float qt[64 * LST];
  __shared__ float wt[32 * LST];
  const int tid = threadIdx.x;

  if (blockIdx.x < 4096) {
    const int qb0 = (blockIdx.x & 15) * 64;
    const int wb  = (blockIdx.x >> 4) & 63;
    const int wr0 = LBL_ROWS + wb * 32;
    const int h   = blockIdx.x >> 10;

    for (int idx = tid; idx < 96 * 20; idx += 128) {
      const int row = idx / 20, c4 = idx % 20;
      int col, lcol;
      if (c4 < 4)       { col = h * 16 + c4 * 4;              lcol = c4 * 4; }
      else if (c4 < 12) { col = 64 + h * 32 + (c4 - 4) * 4;   lcol = 16 + (c4 - 4) * 4; }
      else              { col = 192 + h * 32 + (c4 - 12) * 4; lcol = 48 + (c4 - 12) * 4; }
      const bool isq = row < 64;
      const int grow = isq ? (qb0 + row) : (wr0 + row - 64);
      const float4 v = *(const float4*)((isq ? qcomp : wcomp) + (size_t)grow * CROW + col);
      float* dst = (isq ? qt + row * LST : wt + (row - 64) * LST) + lcol;
      dst[0] = v.x; dst[1] = v.y; dst[2] = v.z; dst[3] = v.w;
    }
    __syncthreads();

    const int qg = tid >> 3;
    const int wg = tid & 7;
    const float* qb = qt + (qg * 4) * LST;
    const float* wbp = wt + (wg * 4) * LST;

    float pd[4][4] = {{0.f}}, pf[4][4] = {{0.f}};
#pragma unroll
    for (int kc = 0; kc < 8; kc++) {
      float2 qv[4], wv[4];
#pragma unroll
      for (int i = 0; i < 4; i++) qv[i] = *(const float2*)(qb + i * LST + 2 * kc);
#pragma unroll
      for (int j = 0; j < 4; j++) wv[j] = *(const float2*)(wbp + j * LST + 2 * kc);
#pragma unroll
      for (int i = 0; i < 4; i++)
#pragma unroll
        for (int j = 0; j < 4; j++) {
          pd[i][j] = fmaf(qv[i].x, wv[j].x, pd[i][j]);
          pd[i][j] = fmaf(qv[i].y, wv[j].y, pd[i][j]);
        }
    }
#pragma unroll 8
    for (int kc = 0; kc < 32; kc++) {
      float2 qv[4], wv[4];
#pragma unroll
      for (int i = 0; i < 4; i++) qv[i] = *(const float2*)(qb + i * LST + 16 + 2 * kc);
#pragma unroll
      for (int j = 0; j < 4; j++) wv[j] = *(const float2*)(wbp + j * LST + 16 + 2 * kc);
#pragma unroll
      for (int i = 0; i < 4; i++)
#pragma unroll
        for (int j = 0; j < 4; j++) {
          pf[i][j] = fmaf(qv[i].x, wv[j].x, pf[i][j]);
          pf[i][j] = fmaf(qv[i].y, wv[j].y, pf[i][j]);
        }
    }

#pragma unroll
    for (int i = 0; i < 4; i++) {
      float acc = 0.f;
#pragma unroll
      for (int j = 0; j < 4; j++) acc += pd[i][j] * pf[i][j];
#pragma unroll
      for (int off = 1; off < 8; off <<= 1) acc += __shfl_xor(acc, off, 64);
      if (wg == 0) atomicAdd(&negparts[wb * B_Q + qb0 + qg * 4 + i], acc);
    }
  } else {
    // ---------------- pos path ----------------
    const int g = (blockIdx.x - 4096) * 32 + (tid >> 2);
    const int h = tid & 3;
    const float* q = qcomp + (size_t)(g >> 3) * CROW;
    const float* w = wcomp + (size_t)g * CROW;
    float pd = 0.f, pf = 0.f;
#pragma unroll
    for (int c = 0; c < 4; c++) {
      const float4 qv = *(const float4*)(q + h * 16 + c * 4);
      const float4 wv = *(const float4*)(w + h * 16 + c * 4);
      pd += qv.x * wv.x + qv.y * wv.y + qv.z * wv.z + qv.w * wv.w;
    }
#pragma unroll
    for (int r = 0; r < 2; r++)
#pragma unroll
      for (int c = 0; c < 8; c++) {
        const float4 qv = *(const float4*)(q + 64 + r * 128 + h * 32 + c * 4);
        const float4 wv = *(const float4*)(w + 64 + r * 128 + h * 32 + c * 4);
        pf += qv.x * wv.x + qv.y * wv.y + qv.z * wv.z + qv.w * wv.w;
      }
    float sc = pd * pf;
    sc += __shfl_xor(sc, 1, 64);
    sc += __shfl_xor(sc, 2, 64);
    if (h == 0) pos[g] = sc;
  }
}

__global__ __launch_bounds__(1024) void k_loss(const float* __restrict__ pos,
                                               const float* __restrict__ negparts,
                                               const float* __restrict__ lmask,
                                               float* __restrict__ out) {
  const int b = threadIdx.x;
  float lp[8];
  float possum = 0.f;
#pragma unroll
  for (int k = 0; k < 8; k++) { lp[k] = pos[b * 8 + k]; possum += lp[k]; }
  float negsum = 0.f;
#pragma unroll 8
  for (int c = 0; c < 64; c++) negsum += negparts[c * B_Q + b];
  const float Z = possum + negsum + 2.056e-5f;  // + 2056 * 1e-8
  const float logZ = logf(Z);
  float local = 0.f, lsum = 0.f;
#pragma unroll
  for (int k = 0; k < 8; k++) {
    const float lm = lmask[b * 8 + k];
    local += lm * (logf(lp[k] + 1e-8f) - logZ);
    lsum += lm;
  }
  local = wave_sum(local);
  lsum = wave_sum(lsum);
  __shared__ float r1[16], r2[16];
  const int wid = b >> 6;
  if ((b & 63) == 0) { r1[wid] = local; r2[wid] = lsum; }
  __syncthreads();
  if (b == 0) {
    float t1 = 0.f, t2 = 0.f;
    for (int wv = 0; wv < 16; wv++) { t1 += r1[wv]; t2 += r2[wv]; }
    out[0] = -t1 / (t2 + 1e-6f);
  }
}

extern "C" void kernel_launch(void* const* d_in, const int* in_sizes, int n_in,
                              void* d_out, int out_size, void* d_ws, size_t ws_size,
                              hipStream_t stream) {
  const int* indices  = (const int*)d_in[0];
  const float* mask   = (const float*)d_in[1];
  const int* labels   = (const int*)d_in[2];
  const float* lmask  = (const float*)d_in[3];
  const int* negidx   = (const int*)d_in[4];
  const float* embed  = (const float*)d_in[5];
  const float* kern   = (const float*)d_in[6];
  const float* omega  = (const float*)d_in[7];
  const float* anchors= (const float*)d_in[8];
  float* out = (float*)d_out;

  float* ws = (float*)d_ws;
  float* anchT    = ws;                            // 1024
  float* qcomp    = anchT + 1024;                  // 1024*320
  float* wcomp    = qcomp + (size_t)B_Q * CROW;    // 10240*320
  float* wgath    = wcomp + (size_t)W_ROWS * CROW; // 256*10240
  float* pos      = wgath + (size_t)D_EMB * W_ROWS;// 8192
  float* negparts = pos + LBL_ROWS;                // 64*1024
  int*   jidx     = (int*)(negparts + 64 * B_Q);   // 10240
  int*   sorted   = jidx + W_ROWS;                 // 10240
  int*   hist     = sorted + W_ROWS;               // 2048
  int*   slotmap  = hist + 2048;                   // 131072

  k_prep<<<777, 256, 0, stream>>>(anchors, anchT, negparts, hist, slotmap);
  k_mark<<<40, 256, 0, stream>>>(labels, negidx, jidx, hist);
  k_scan<<<1, 256, 0, stream>>>(hist);
  k_scatter<<<40, 256, 0, stream>>>(jidx, hist, sorted, slotmap);
  k_gather<<<3072, 256, 0, stream>>>(kern, slotmap, wgath, indices, mask, embed,
                                     anchT, omega, qcomp);
  k_wproj<<<W_ROWS / RPB, 256, 0, stream>>>(sorted, jidx, slotmap, wgath, anchT, omega, wcomp);
  k_score<<<4096 + 256, 128, 0, stream>>>(qcomp, wcomp, negparts, pos);
  k_loss<<<1, 1024, 0, stream>>>(pos, negparts, lmask, out);
}

// Round 5
// 357.117 us; speedup vs baseline: 1.0964x; 1.0964x over previous
//
#include <hip/hip_runtime.h>
#include <math.h>

#define B_Q 1024
#define L_SEQ 128
#define D_EMB 256
#define NLAB 131072
#define LBL_ROWS 8192
#define NEG_ROWS 2048
#define W_ROWS 10240
#define CROW 320   // compact row: 64 poly + 256 prf
#define RPB 32     // wrows rows per block
#define SXS 258    // sx row stride (<=2-way LDS conflicts, float2-aligned)
#define QST 84     // k_score q-tile LDS stride (floats, 16B-multiple)
#define NWT 32     // neg w-tiles (2048/64)

__device__ __forceinline__ float wave_sum(float v) {
#pragma unroll
  for (int off = 32; off > 0; off >>= 1) v += __shfl_xor(v, off, 64);
  return v;
}

// sx: 256 per-head-normalized dims in LDS. t in [0,256). One compact row out.
__device__ __forceinline__ void slay_tail(const float* __restrict__ sx, int t,
                                          const float* __restrict__ anchT,
                                          const float* __restrict__ omega,
                                          float* __restrict__ outrow) {
  if (t < 64) {
    const int h = t >> 4, p = t & 15;
    const float* x = sx + h * 64;
    float d = 0.f;
#pragma unroll
    for (int dd = 0; dd < 64; dd++) d = fmaf(x[dd], anchT[dd * 16 + p], d);
    d = fminf(fmaxf(d, -1.0f), 1.0f);
    outrow[h * 16 + p] = d * d * 0.25f;
  }
  {
    const int r = t >> 7;
    const int h = (t >> 5) & 3;
    const float* x = sx + h * 64;
    const float* om = omega + (size_t)(t >> 5) * 2048 + (t & 31);
    float d = 0.f;
#pragma unroll
    for (int dd = 0; dd < 64; dd++) d = fmaf(x[dd], om[dd * 32], d);
    const float proj = d * 0.125f;
    const float s = r ? 1.70710592763316f : 0.29289307236691f;
    const float w = r ? 0.07322326809171f : 0.42677648190829f;
    float arg = proj * sqrtf(2.0f * s) - s;
    arg = fminf(fmaxf(arg, -20.0f), 20.0f);
    outrow[64 + t] = expf(arg) * (sqrtf(w) / sqrtf(32.000001f));
  }
}

// block 0: anchors. block 1: sort pipeline (vectorized, LDS hist+scan+scatter).
__global__ __launch_bounds__(256) void k_setup(const float* __restrict__ anchors,
                                               const int* __restrict__ labels,
                                               const int* __restrict__ negidx,
                                               float* __restrict__ anchT,
                                               int* __restrict__ jidx,
                                               int* __restrict__ sorted) {
  __shared__ int shist[2048];
  __shared__ int s2[256];
  const int t = threadIdx.x, bx = blockIdx.x;
  if (bx == 0) {
    if (t < 64) {
      for (int p = 0; p < 16; p++) {
        const float v = anchors[p * 64 + t];
        const float n = sqrtf(wave_sum(v * v));
        anchT[t * 16 + p] = v / n;
      }
    }
  } else {
    for (int i = t; i < 2048; i += 256) shist[i] = 0;
    __syncthreads();
    int4 lv[8], nv[2];
#pragma unroll
    for (int e = 0; e < 8; e++) {
      int4 v = ((const int4*)labels)[e * 256 + t];
      v.x = max(v.x, 0); v.y = max(v.y, 0); v.z = max(v.z, 0); v.w = max(v.w, 0);
      lv[e] = v;
      ((int4*)jidx)[e * 256 + t] = v;
      atomicAdd(&shist[v.x >> 6], 1); atomicAdd(&shist[v.y >> 6], 1);
      atomicAdd(&shist[v.z >> 6], 1); atomicAdd(&shist[v.w >> 6], 1);
    }
#pragma unroll
    for (int e = 0; e < 2; e++) {
      const int4 v = ((const int4*)negidx)[e * 256 + t];
      nv[e] = v;
      ((int4*)jidx)[2048 + e * 256 + t] = v;
      atomicAdd(&shist[v.x >> 6], 1); atomicAdd(&shist[v.y >> 6], 1);
      atomicAdd(&shist[v.z >> 6], 1); atomicAdd(&shist[v.w >> 6], 1);
    }
    __syncthreads();
    // exclusive scan (8 per thread + Hillis-Steele)
    int v[8]; int sum = 0;
#pragma unroll
    for (int e = 0; e < 8; e++) { v[e] = shist[t * 8 + e]; sum += v[e]; }
    s2[t] = sum; __syncthreads();
    for (int off = 1; off < 256; off <<= 1) {
      const int x = s2[t];
      const int y = (t >= off) ? s2[t - off] : 0;
      __syncthreads();
      s2[t] = x + y;
      __syncthreads();
    }
    int run = s2[t] - sum;
#pragma unroll
    for (int e = 0; e < 8; e++) { shist[t * 8 + e] = run; run += v[e]; }
    __syncthreads();
    // scatter from registers
#pragma unroll
    for (int e = 0; e < 8; e++) {
      const int i = (e * 256 + t) * 4;
      sorted[atomicAdd(&shist[lv[e].x >> 6], 1)] = i;
      sorted[atomicAdd(&shist[lv[e].y >> 6], 1)] = i + 1;
      sorted[atomicAdd(&shist[lv[e].z >> 6], 1)] = i + 2;
      sorted[atomicAdd(&shist[lv[e].w >> 6], 1)] = i + 3;
    }
#pragma unroll
    for (int e = 0; e < 2; e++) {
      const int i = LBL_ROWS + (e * 256 + t) * 4;
      sorted[atomicAdd(&shist[nv[e].x >> 6], 1)] = i;
      sorted[atomicAdd(&shist[nv[e].y >> 6], 1)] = i + 1;
      sorted[atomicAdd(&shist[nv[e].z >> 6], 1)] = i + 2;
      sorted[atomicAdd(&shist[nv[e].w >> 6], 1)] = i + 3;
    }
  }
}

// Fused query + wrows (round-2 structure, measured best for this phase).
__global__ __launch_bounds__(256, 4) void k_feat(const int* __restrict__ indices,
                                                 const float* __restrict__ mask,
                                                 const float* __restrict__ embed,
                                                 const float* __restrict__ kern,
                                                 const float* __restrict__ anchT,
                                                 const float* __restrict__ omega,
                                                 const int* __restrict__ jidx,
                                                 const int* __restrict__ sorted,
                                                 float* __restrict__ qcomp,
                                                 float* __restrict__ wcomp) {
  __shared__ __align__(16) float smem[9504];
  const int tid = threadIdx.x;

  if (blockIdx.x < B_Q) {
    // ---------------- query path ----------------
    const int b = blockIdx.x, t = tid;
    const int wv = t >> 6, ln = t & 63;
    int* sidx = (int*)smem;                 // 128
    float* smask = smem + 128;              // 128
    float4* spart = (float4*)(smem + 256);  // 256 float4
    float* smsum = smem + 1280;             // 4
    float* sx = smem + 1296;                // 256
    if (t < L_SEQ) { sidx[t] = indices[b * L_SEQ + t]; smask[t] = mask[b * L_SEQ + t]; }
    __syncthreads();
    float4 acc = {0.f, 0.f, 0.f, 0.f};
    float msum = 0.f;
#pragma unroll 8
    for (int l = wv * 32; l < wv * 32 + 32; l++) {
      const float m = smask[l];
      msum += m;
      const float4 e = *(const float4*)(embed + (size_t)sidx[l] * D_EMB + ln * 4);
      acc.x = fmaf(e.x, m, acc.x); acc.y = fmaf(e.y, m, acc.y);
      acc.z = fmaf(e.z, m, acc.z); acc.w = fmaf(e.w, m, acc.w);
    }
    spart[wv * 64 + ln] = acc;
    if (ln == 0) smsum[wv] = msum;
    __syncthreads();
    const float* spf = (const float*)spart;
    float q = spf[t] + spf[256 + t] + spf[512 + t] + spf[768 + t];
    const float mt = smsum[0] + smsum[1] + smsum[2] + smsum[3];
    q /= fmaxf(mt, 1.0f);
    const float ss = wave_sum(q * q);  // wave == head
    sx[t] = q / fmaxf(sqrtf(ss), 1e-4f);
    __syncthreads();
    slay_tail(sx, t, anchT, omega, qcomp + (size_t)b * CROW);
  } else {
    // ---------------- wrows path ----------------
    const int lb = blockIdx.x - B_Q;   // [0, 320)
    int* sj = (int*)smem;              // 32
    int* ssid = (int*)smem + 32;       // 32
    float* rnorm = smem + 64;          // 128 (reciprocal norms, [row][head])
    float* sq = smem + 192;            // 32*33 = 1056 (ssq partials, padded)
    float* sx = smem + 1248;           // 32*258 = 8256
    const int cb = (lb & 7) * 40 + (lb >> 3);
    const int i0 = cb * RPB;

    if (tid < RPB) {
      const int sid = sorted[i0 + tid];
      ssid[tid] = sid;
      sj[tid] = jidx[sid];
    }
    __syncthreads();

    // gather: thread = (dloc, row); dim = it*8+dloc
    {
      const int row = tid & 31, dloc = tid >> 5;
      const float* kbase = kern + ((size_t)dloc << 17) + (size_t)sj[row];
      float ssq[4] = {0.f, 0.f, 0.f, 0.f};
#pragma unroll
      for (int it = 0; it < 32; it++) {
        const float v = kbase[(size_t)it << 20];  // dim = it*8+dloc
        sx[row * SXS + it * 8 + dloc] = v;
        ssq[it >> 3] = fmaf(v, v, ssq[it >> 3]);
      }
#pragma unroll
      for (int h = 0; h < 4; h++) sq[row * 33 + dloc * 4 + h] = ssq[h];
    }
    __syncthreads();
    if (tid < 128) {
      const int r2 = tid >> 2, h = tid & 3;
      float s = 0.f;
#pragma unroll
      for (int dl = 0; dl < 8; dl++) s += sq[r2 * 33 + dl * 4 + h];
      rnorm[r2 * 4 + h] = 1.0f / fmaxf(sqrtf(s), 1e-4f);
    }
    __syncthreads();

    // prf: thread = (r,h,m); omega loaded once per block for 32 rows.
    {
      const int hh = (tid >> 5) & 3, r = tid >> 7;
      const float* om = omega + (size_t)(tid >> 5) * 2048 + (tid & 31);
      const float s = r ? 1.70710592763316f : 0.29289307236691f;
      const float w = r ? 0.07322326809171f : 0.42677648190829f;
      const float sc = sqrtf(2.0f * s);
      const float outs = sqrtf(w) / sqrtf(32.000001f);
#pragma unroll
      for (int half = 0; half < 2; half++) {
        float acc[16];
#pragma unroll
        for (int rq = 0; rq < 16; rq++) acc[rq] = 0.f;
#pragma unroll
        for (int dd = 0; dd < 64; dd += 2) {
          const float o0 = om[dd * 32], o1 = om[dd * 32 + 32];
#pragma unroll
          for (int rq = 0; rq < 16; rq++) {
            const float2 xv = *(const float2*)(sx + (half * 16 + rq) * SXS + hh * 64 + dd);
            acc[rq] = fmaf(xv.x, o0, fmaf(xv.y, o1, acc[rq]));
          }
        }
#pragma unroll
        for (int rq = 0; rq < 16; rq++) {
          const int row = half * 16 + rq;
          float arg = acc[rq] * 0.125f * rnorm[row * 4 + hh] * sc - s;
          arg = fminf(fmaxf(arg, -20.0f), 20.0f);
          wcomp[(size_t)ssid[row] * CROW + 64 + tid] = expf(arg) * outs;
        }
      }
    }

    // poly: thread = (hp, rowgroup); 8 rows each, 2 at a time.
    {
      const int hp = tid & 63, rp = tid >> 6;
      const int h = hp >> 4, p = hp & 15;
#pragma unroll
      for (int pr = 0; pr < 4; pr++) {
        const int r0 = rp * 8 + pr * 2;
        const float* x0 = sx + r0 * SXS + h * 64;
        const float* x1 = x0 + SXS;
        float d0 = 0.f, d1 = 0.f;
#pragma unroll
        for (int dd = 0; dd < 64; dd++) {
          const float a = anchT[dd * 16 + p];
          d0 = fmaf(x0[dd], a, d0);
          d1 = fmaf(x1[dd], a, d1);
        }
        d0 *= rnorm[r0 * 4 + h];
        d1 *= rnorm[(r0 + 1) * 4 + h];
        d0 = fminf(fmaxf(d0, -1.0f), 1.0f);
        d1 = fminf(fmaxf(d1, -1.0f), 1.0f);
        wcomp[(size_t)ssid[r0] * CROW + h * 16 + p]     = d0 * d0 * 0.25f;
        wcomp[(size_t)ssid[r0 + 1] * CROW + h * 16 + p] = d1 * d1 * 0.25f;
      }
    }
  }
}

// Rebuilt scores.
// blocks [0,256): neg tiles 128q x 64w, 8x4 register tile, 4 heads folded.
//   Q staged row-major (reads broadcast, free); W staged TRANSPOSED
//   (swt[dim][wrow], compute reads stride-1 b128, conflict-free).
//   Each (qt,wt) owned by one block -> plain stores, no atomics/zeroing.
// blocks [256,384): pos path.
__global__ __launch_bounds__(256) void k_score(const float* __restrict__ qcomp,
                                               const float* __restrict__ wcomp,
                                               float* __restrict__ negparts,
                                               float* __restrict__ pos) {
  __shared__ __align__(16) float sq[128 * QST];   // 43008 B
  __shared__ __align__(16) float swt[80 * 64];    // 20480 B
  const int tid = threadIdx.x;

  if (blockIdx.x < 256) {
    const int qt = blockIdx.x & 7;          // q-tile
    const int wb = blockIdx.x >> 3;         // w-tile [0,32)
    const int q0 = qt * 128;
    const int wr0 = LBL_ROWS + wb * 64;
    const int qg = tid >> 4;                // [0,16) -> 8 q-rows each
    const int wg = tid & 15;                // [0,16) -> 4 w-cols each

    float acc[8][4];
#pragma unroll
    for (int i = 0; i < 8; i++)
#pragma unroll
      for (int j = 0; j < 4; j++) acc[i][j] = 0.f;

    for (int h = 0; h < 4; h++) {
      // ---- stage Q tile: 128 rows x 20 float4, row-major stride QST ----
#pragma unroll
      for (int k = 0; k < 10; k++) {
        const int idx = k * 256 + tid;
        const int row = idx / 20, c4 = idx % 20;
        int col;
        if (c4 < 4)       col = h * 16 + c4 * 4;
        else if (c4 < 12) col = 64 + h * 32 + (c4 - 4) * 4;
        else              col = 192 + h * 32 + (c4 - 12) * 4;
        const float4 v = *(const float4*)(qcomp + (size_t)(q0 + row) * CROW + col);
        *(float4*)(sq + row * QST + c4 * 4) = v;
      }
      // ---- stage W tile transposed: swt[dim][wrow] ----
#pragma unroll
      for (int k = 0; k < 5; k++) {
        const int idx = k * 256 + tid;
        const int row = idx / 20, c4 = idx % 20;
        int col;
        if (c4 < 4)       col = h * 16 + c4 * 4;
        else if (c4 < 12) col = 64 + h * 32 + (c4 - 4) * 4;
        else              col = 192 + h * 32 + (c4 - 12) * 4;
        const float4 v = *(const float4*)(wcomp + (size_t)(wr0 + row) * CROW + col);
        swt[(c4 * 4 + 0) * 64 + row] = v.x;
        swt[(c4 * 4 + 1) * 64 + row] = v.y;
        swt[(c4 * 4 + 2) * 64 + row] = v.z;
        swt[(c4 * 4 + 3) * 64 + row] = v.w;
      }
      __syncthreads();

      float pd[8][4], pf[8][4];
#pragma unroll
      for (int i = 0; i < 8; i++)
#pragma unroll
        for (int j = 0; j < 4; j++) { pd[i][j] = 0.f; pf[i][j] = 0.f; }

#pragma unroll
      for (int c = 0; c < 20; c++) {
        float4 qv[8];
#pragma unroll
        for (int i = 0; i < 8; i++)
          qv[i] = *(const float4*)(sq + (qg * 8 + i) * QST + c * 4);
#pragma unroll
        for (int k = 0; k < 4; k++) {
          const float4 wvk = *(const float4*)(swt + (c * 4 + k) * 64 + wg * 4);
          if (c < 4) {
#pragma unroll
            for (int i = 0; i < 8; i++) {
              const float qik = ((const float*)&qv[i])[k];
              pd[i][0] = fmaf(qik, wvk.x, pd[i][0]);
              pd[i][1] = fmaf(qik, wvk.y, pd[i][1]);
              pd[i][2] = fmaf(qik, wvk.z, pd[i][2]);
              pd[i][3] = fmaf(qik, wvk.w, pd[i][3]);
            }
          } else {
#pragma unroll
            for (int i = 0; i < 8; i++) {
              const float qik = ((const float*)&qv[i])[k];
              pf[i][0] = fmaf(qik, wvk.x, pf[i][0]);
              pf[i][1] = fmaf(qik, wvk.y, pf[i][1]);
              pf[i][2] = fmaf(qik, wvk.z, pf[i][2]);
              pf[i][3] = fmaf(qik, wvk.w, pf[i][3]);
            }
          }
        }
      }
#pragma unroll
      for (int i = 0; i < 8; i++)
#pragma unroll
        for (int j = 0; j < 4; j++) acc[i][j] = fmaf(pd[i][j], pf[i][j], acc[i][j]);
      __syncthreads();  // before next head overwrites LDS
    }

    // reduce over w: sum 4 cols, then across wg lanes (16-lane groups)
#pragma unroll
    for (int i = 0; i < 8; i++) {
      float r = acc[i][0] + acc[i][1] + acc[i][2] + acc[i][3];
      r += __shfl_xor(r, 1, 64);
      r += __shfl_xor(r, 2, 64);
      r += __shfl_xor(r, 4, 64);
      r += __shfl_xor(r, 8, 64);
      if (wg == 0) negparts[wb * B_Q + q0 + qg * 8 + i] = r;
    }
  } else {
    // ---------------- pos path ----------------
    const int g = (blockIdx.x - 256) * 64 + (tid >> 2);
    const int h = tid & 3;
    const float* q = qcomp + (size_t)(g >> 3) * CROW;
    const float* w = wcomp + (size_t)g * CROW;
    float pd = 0.f, pf = 0.f;
#pragma unroll
    for (int c = 0; c < 4; c++) {
      const float4 qv = *(const float4*)(q + h * 16 + c * 4);
      const float4 wv = *(const float4*)(w + h * 16 + c * 4);
      pd += qv.x * wv.x + qv.y * wv.y + qv.z * wv.z + qv.w * wv.w;
    }
#pragma unroll
    for (int r = 0; r < 2; r++)
#pragma unroll
      for (int c = 0; c < 8; c++) {
        const float4 qv = *(const float4*)(q + 64 + r * 128 + h * 32 + c * 4);
        const float4 wv = *(const float4*)(w + 64 + r * 128 + h * 32 + c * 4);
        pf += qv.x * wv.x + qv.y * wv.y + qv.z * wv.z + qv.w * wv.w;
      }
    float sc = pd * pf;
    sc += __shfl_xor(sc, 1, 64);
    sc += __shfl_xor(sc, 2, 64);
    if (h == 0) pos[g] = sc;
  }
}

__global__ __launch_bounds__(1024) void k_loss(const float* __restrict__ pos,
                                               const float* __restrict__ negparts,
                                               const float* __restrict__ lmask,
                                               float* __restrict__ out) {
  const int b = threadIdx.x;
  float lp[8];
  float possum = 0.f;
#pragma unroll
  for (int k = 0; k < 8; k++) { lp[k] = pos[b * 8 + k]; possum += lp[k]; }
  float negsum = 0.f;
#pragma unroll 8
  for (int c = 0; c < NWT; c++) negsum += negparts[c * B_Q + b];
  const float Z = possum + negsum + 2.056e-5f;  // + 2056 * 1e-8
  const float logZ = logf(Z);
  float local = 0.f, lsum = 0.f;
#pragma unroll
  for (int k = 0; k < 8; k++) {
    const float lm = lmask[b * 8 + k];
    local += lm * (logf(lp[k] + 1e-8f) - logZ);
    lsum += lm;
  }
  local = wave_sum(local);
  lsum = wave_sum(lsum);
  __shared__ float r1[16], r2[16];
  const int wid = b >> 6;
  if ((b & 63) == 0) { r1[wid] = local; r2[wid] = lsum; }
  __syncthreads();
  if (b == 0) {
    float t1 = 0.f, t2 = 0.f;
    for (int wv = 0; wv < 16; wv++) { t1 += r1[wv]; t2 += r2[wv]; }
    out[0] = -t1 / (t2 + 1e-6f);
  }
}

extern "C" void kernel_launch(void* const* d_in, const int* in_sizes, int n_in,
                              void* d_out, int out_size, void* d_ws, size_t ws_size,
                              hipStream_t stream) {
  const int* indices  = (const int*)d_in[0];
  const float* mask   = (const float*)d_in[1];
  const int* labels   = (const int*)d_in[2];
  const float* lmask  = (const float*)d_in[3];
  const int* negidx   = (const int*)d_in[4];
  const float* embed  = (const float*)d_in[5];
  const float* kern   = (const float*)d_in[6];
  const float* omega  = (const float*)d_in[7];
  const float* anchors= (const float*)d_in[8];
  float* out = (float*)d_out;

  float* ws = (float*)d_ws;
  float* anchT    = ws;                            // 1024
  float* qcomp    = anchT + 1024;                  // 1024*320
  float* wcomp    = qcomp + (size_t)B_Q * CROW;    // 10240*320
  float* pos      = wcomp + (size_t)W_ROWS * CROW; // 8192
  float* negparts = pos + LBL_ROWS;                // 32*1024
  int*   jidx     = (int*)(negparts + NWT * B_Q);  // 10240
  int*   sorted   = jidx + W_ROWS;                 // 10240

  k_setup<<<2, 256, 0, stream>>>(anchors, labels, negidx, anchT, jidx, sorted);
  k_feat<<<B_Q + W_ROWS / RPB, 256, 0, stream>>>(indices, mask, embed, kern, anchT, omega,
                                                 jidx, sorted, qcomp, wcomp);
  k_score<<<256 + 128, 256, 0, stream>>>(qcomp, wcomp, negparts, pos);
  k_loss<<<1, 1024, 0, stream>>>(pos, negparts, lmask, out);
}

// Round 6
// 338.801 us; speedup vs baseline: 1.1557x; 1.0541x over previous
//
#include <hip/hip_runtime.h>
#include <math.h>

#define B_Q 1024
#define L_SEQ 128
#define D_EMB 256
#define NLAB 131072
#define LBL_ROWS 8192
#define NEG_ROWS 2048
#define W_ROWS 10240
#define CROW 320   // compact row: 64 poly + 256 prf
#define RPB 8      // wrows rows per block (1280 blocks -> 5/CU co-resident)
#define NWB 1280   // wrows blocks (dispatched FIRST)
#define SXS 258    // sx row stride (float2-aligned, <=2-way conflicts)
#define QST 84     // k_score q-tile LDS stride
#define NWT 32     // neg w-tiles (2048/64)

__device__ __forceinline__ float wave_sum(float v) {
#pragma unroll
  for (int off = 32; off > 0; off >>= 1) v += __shfl_xor(v, off, 64);
  return v;
}

// sx: 256 per-head-normalized dims in LDS. t in [0,256). One compact row out.
__device__ __forceinline__ void slay_tail(const float* __restrict__ sx, int t,
                                          const float* __restrict__ anchT,
                                          const float* __restrict__ omega,
                                          float* __restrict__ outrow) {
  if (t < 64) {
    const int h = t >> 4, p = t & 15;
    const float* x = sx + h * 64;
    float d = 0.f;
#pragma unroll
    for (int dd = 0; dd < 64; dd++) d = fmaf(x[dd], anchT[dd * 16 + p], d);
    d = fminf(fmaxf(d, -1.0f), 1.0f);
    outrow[h * 16 + p] = d * d * 0.25f;
  }
  {
    const int r = t >> 7;
    const int h = (t >> 5) & 3;
    const float* x = sx + h * 64;
    const float* om = omega + (size_t)(t >> 5) * 2048 + (t & 31);
    float d = 0.f;
#pragma unroll
    for (int dd = 0; dd < 64; dd++) d = fmaf(x[dd], om[dd * 32], d);
    const float proj = d * 0.125f;
    const float s = r ? 1.70710592763316f : 0.29289307236691f;
    const float w = r ? 0.07322326809171f : 0.42677648190829f;
    float arg = proj * sqrtf(2.0f * s) - s;
    arg = fminf(fmaxf(arg, -20.0f), 20.0f);
    outrow[64 + t] = expf(arg) * (sqrtf(w) / sqrtf(32.000001f));
  }
}

// block 0: anchors. block 1: sort pipeline (vectorized, LDS hist+scan+scatter).
__global__ __launch_bounds__(256) void k_setup(const float* __restrict__ anchors,
                                               const int* __restrict__ labels,
                                               const int* __restrict__ negidx,
                                               float* __restrict__ anchT,
                                               int* __restrict__ jidx,
                                               int* __restrict__ sorted) {
  __shared__ int shist[2048];
  __shared__ int s2[256];
  const int t = threadIdx.x, bx = blockIdx.x;
  if (bx == 0) {
    if (t < 64) {
      for (int p = 0; p < 16; p++) {
        const float v = anchors[p * 64 + t];
        const float n = sqrtf(wave_sum(v * v));
        anchT[t * 16 + p] = v / n;
      }
    }
  } else {
    for (int i = t; i < 2048; i += 256) shist[i] = 0;
    __syncthreads();
    int4 lv[8], nv[2];
#pragma unroll
    for (int e = 0; e < 8; e++) {
      int4 v = ((const int4*)labels)[e * 256 + t];
      v.x = max(v.x, 0); v.y = max(v.y, 0); v.z = max(v.z, 0); v.w = max(v.w, 0);
      lv[e] = v;
      ((int4*)jidx)[e * 256 + t] = v;
      atomicAdd(&shist[v.x >> 6], 1); atomicAdd(&shist[v.y >> 6], 1);
      atomicAdd(&shist[v.z >> 6], 1); atomicAdd(&shist[v.w >> 6], 1);
    }
#pragma unroll
    for (int e = 0; e < 2; e++) {
      const int4 v = ((const int4*)negidx)[e * 256 + t];
      nv[e] = v;
      ((int4*)jidx)[2048 + e * 256 + t] = v;
      atomicAdd(&shist[v.x >> 6], 1); atomicAdd(&shist[v.y >> 6], 1);
      atomicAdd(&shist[v.z >> 6], 1); atomicAdd(&shist[v.w >> 6], 1);
    }
    __syncthreads();
    // exclusive scan (8 per thread + Hillis-Steele)
    int v[8]; int sum = 0;
#pragma unroll
    for (int e = 0; e < 8; e++) { v[e] = shist[t * 8 + e]; sum += v[e]; }
    s2[t] = sum; __syncthreads();
    for (int off = 1; off < 256; off <<= 1) {
      const int x = s2[t];
      const int y = (t >= off) ? s2[t - off] : 0;
      __syncthreads();
      s2[t] = x + y;
      __syncthreads();
    }
    int run = s2[t] - sum;
#pragma unroll
    for (int e = 0; e < 8; e++) { shist[t * 8 + e] = run; run += v[e]; }
    __syncthreads();
    // scatter from registers
#pragma unroll
    for (int e = 0; e < 8; e++) {
      const int i = (e * 256 + t) * 4;
      sorted[atomicAdd(&shist[lv[e].x >> 6], 1)] = i;
      sorted[atomicAdd(&shist[lv[e].y >> 6], 1)] = i + 1;
      sorted[atomicAdd(&shist[lv[e].z >> 6], 1)] = i + 2;
      sorted[atomicAdd(&shist[lv[e].w >> 6], 1)] = i + 3;
    }
#pragma unroll
    for (int e = 0; e < 2; e++) {
      const int i = LBL_ROWS + (e * 256 + t) * 4;
      sorted[atomicAdd(&shist[nv[e].x >> 6], 1)] = i;
      sorted[atomicAdd(&shist[nv[e].y >> 6], 1)] = i + 1;
      sorted[atomicAdd(&shist[nv[e].z >> 6], 1)] = i + 2;
      sorted[atomicAdd(&shist[nv[e].w >> 6], 1)] = i + 3;
    }
  }
}

// Fused wrows + query. wrows blocks FIRST ([0,1280)) so the latency-bound
// gather is co-resident with the streaming query phase ([1280,2304)).
// wrows: 8 rows/block, thread=dim, 8 register-batched loads in flight,
// norms via wave_sum (wave == head), no LDS partial passes.
__global__ __launch_bounds__(256) void k_feat(const int* __restrict__ indices,
                                              const float* __restrict__ mask,
                                              const float* __restrict__ embed,
                                              const float* __restrict__ kern,
                                              const float* __restrict__ anchT,
                                              const float* __restrict__ omega,
                                              const int* __restrict__ jidx,
                                              const int* __restrict__ sorted,
                                              float* __restrict__ qcomp,
                                              float* __restrict__ wcomp) {
  __shared__ __align__(16) float smem[2112];
  const int tid = threadIdx.x;

  if (blockIdx.x < NWB) {
    // ---------------- wrows path ----------------
    const int lb = blockIdx.x;         // [0, 1280)
    int* sj = (int*)smem;              // 8
    int* ssid = (int*)smem + 8;        // 8
    float* rnorm = smem + 16;          // 32 ([row][head] reciprocal norms)
    float* sx = smem + 48;             // 8*258 = 2064
    // XCD-contiguous remap over sorted-j bands (1280 = 8*160)
    const int cb = (lb & 7) * 160 + (lb >> 3);
    const int i0 = cb * RPB;

    if (tid < RPB) {
      const int sid = sorted[i0 + tid];
      ssid[tid] = sid;
      sj[tid] = jidx[sid];
    }
    __syncthreads();

    // gather: thread = dim; all 8 independent loads issued before use
    {
      const float* kbase = kern + ((size_t)tid << 17);  // tid * NLAB
      float vv[8];
#pragma unroll
      for (int k = 0; k < RPB; k++) vv[k] = kbase[sj[k]];
#pragma unroll
      for (int k = 0; k < RPB; k++) {
        sx[k * SXS + tid] = vv[k];
        const float ss = wave_sum(vv[k] * vv[k]);  // wave w == head w dims
        if ((tid & 63) == 0) rnorm[k * 4 + (tid >> 6)] = 1.0f / fmaxf(sqrtf(ss), 1e-4f);
      }
    }
    __syncthreads();

    // prf: thread = (r,h,m); omega loaded once, reused for 8 rows; norm folded
    {
      const int hh = (tid >> 5) & 3, r = tid >> 7;
      const float* om = omega + (size_t)(tid >> 5) * 2048 + (tid & 31);
      const float s = r ? 1.70710592763316f : 0.29289307236691f;
      const float w = r ? 0.07322326809171f : 0.42677648190829f;
      const float sc = sqrtf(2.0f * s);
      const float outs = sqrtf(w) / sqrtf(32.000001f);
      float acc[RPB];
#pragma unroll
      for (int k = 0; k < RPB; k++) acc[k] = 0.f;
#pragma unroll
      for (int dd = 0; dd < 64; dd += 2) {
        const float o0 = om[dd * 32], o1 = om[dd * 32 + 32];
#pragma unroll
        for (int k = 0; k < RPB; k++) {
          const float2 xv = *(const float2*)(sx + k * SXS + hh * 64 + dd);
          acc[k] = fmaf(xv.x, o0, fmaf(xv.y, o1, acc[k]));
        }
      }
#pragma unroll
      for (int k = 0; k < RPB; k++) {
        float arg = acc[k] * 0.125f * rnorm[k * 4 + hh] * sc - s;
        arg = fminf(fmaxf(arg, -20.0f), 20.0f);
        wcomp[(size_t)ssid[k] * CROW + 64 + tid] = expf(arg) * outs;
      }
    }

    // poly: thread = (hp, rowpair); 2 rows each; norm folded
    {
      const int hp = tid & 63, rp = tid >> 6;
      const int h = hp >> 4, p = hp & 15;
      const int r0 = rp * 2;
      const float* x0 = sx + r0 * SXS + h * 64;
      const float* x1 = x0 + SXS;
      float d0 = 0.f, d1 = 0.f;
#pragma unroll
      for (int dd = 0; dd < 64; dd++) {
        const float a = anchT[dd * 16 + p];
        d0 = fmaf(x0[dd], a, d0);
        d1 = fmaf(x1[dd], a, d1);
      }
      d0 *= rnorm[r0 * 4 + h];
      d1 *= rnorm[(r0 + 1) * 4 + h];
      d0 = fminf(fmaxf(d0, -1.0f), 1.0f);
      d1 = fminf(fmaxf(d1, -1.0f), 1.0f);
      wcomp[(size_t)ssid[r0] * CROW + h * 16 + p]     = d0 * d0 * 0.25f;
      wcomp[(size_t)ssid[r0 + 1] * CROW + h * 16 + p] = d1 * d1 * 0.25f;
    }
  } else {
    // ---------------- query path ----------------
    const int b = blockIdx.x - NWB, t = tid;
    const int wv = t >> 6, ln = t & 63;
    int* sidx = (int*)smem;                 // 128
    float* smask = smem + 128;              // 128
    float4* spart = (float4*)(smem + 256);  // 256 float4
    float* smsum = smem + 1280;             // 4
    float* sx = smem + 1296;                // 256
    if (t < L_SEQ) { sidx[t] = indices[b * L_SEQ + t]; smask[t] = mask[b * L_SEQ + t]; }
    __syncthreads();
    float4 acc = {0.f, 0.f, 0.f, 0.f};
    float msum = 0.f;
#pragma unroll 8
    for (int l = wv * 32; l < wv * 32 + 32; l++) {
      const float m = smask[l];
      msum += m;
      const float4 e = *(const float4*)(embed + (size_t)sidx[l] * D_EMB + ln * 4);
      acc.x = fmaf(e.x, m, acc.x); acc.y = fmaf(e.y, m, acc.y);
      acc.z = fmaf(e.z, m, acc.z); acc.w = fmaf(e.w, m, acc.w);
    }
    spart[wv * 64 + ln] = acc;
    if (ln == 0) smsum[wv] = msum;
    __syncthreads();
    const float* spf = (const float*)spart;
    float q = spf[t] + spf[256 + t] + spf[512 + t] + spf[768 + t];
    const float mt = smsum[0] + smsum[1] + smsum[2] + smsum[3];
    q /= fmaxf(mt, 1.0f);
    const float ss = wave_sum(q * q);  // wave == head
    sx[t] = q / fmaxf(sqrtf(ss), 1e-4f);
    __syncthreads();
    slay_tail(sx, t, anchT, omega, qcomp + (size_t)b * CROW);
  }
}

// blocks [0,256): neg tiles 128q x 64w, 8x4 register tile, 4 heads folded.
//   Q staged row-major (reads broadcast); W staged TRANSPOSED (stride-1 reads).
//   Each (qt,wt) owned by one block -> plain stores, no atomics/zeroing.
// blocks [256,384): pos path.
__global__ __launch_bounds__(256) void k_score(const float* __restrict__ qcomp,
                                               const float* __restrict__ wcomp,
                                               float* __restrict__ negparts,
                                               float* __restrict__ pos) {
  __shared__ __align__(16) float sq[128 * QST];   // 43008 B
  __shared__ __align__(16) float swt[80 * 64];    // 20480 B
  const int tid = threadIdx.x;

  if (blockIdx.x < 256) {
    const int qt = blockIdx.x & 7;          // q-tile
    const int wb = blockIdx.x >> 3;         // w-tile [0,32)
    const int q0 = qt * 128;
    const int wr0 = LBL_ROWS + wb * 64;
    const int qg = tid >> 4;                // [0,16) -> 8 q-rows each
    const int wg = tid & 15;                // [0,16) -> 4 w-cols each

    float acc[8][4];
#pragma unroll
    for (int i = 0; i < 8; i++)
#pragma unroll
      for (int j = 0; j < 4; j++) acc[i][j] = 0.f;

    for (int h = 0; h < 4; h++) {
      // ---- stage Q tile: 128 rows x 20 float4, row-major stride QST ----
#pragma unroll
      for (int k = 0; k < 10; k++) {
        const int idx = k * 256 + tid;
        const int row = idx / 20, c4 = idx % 20;
        int col;
        if (c4 < 4)       col = h * 16 + c4 * 4;
        else if (c4 < 12) col = 64 + h * 32 + (c4 - 4) * 4;
        else              col = 192 + h * 32 + (c4 - 12) * 4;
        const float4 v = *(const float4*)(qcomp + (size_t)(q0 + row) * CROW + col);
        *(float4*)(sq + row * QST + c4 * 4) = v;
      }
      // ---- stage W tile transposed: swt[dim][wrow] ----
#pragma unroll
      for (int k = 0; k < 5; k++) {
        const int idx = k * 256 + tid;
        const int row = idx / 20, c4 = idx % 20;
        int col;
        if (c4 < 4)       col = h * 16 + c4 * 4;
        else if (c4 < 12) col = 64 + h * 32 + (c4 - 4) * 4;
        else              col = 192 + h * 32 + (c4 - 12) * 4;
        const float4 v = *(const float4*)(wcomp + (size_t)(wr0 + row) * CROW + col);
        swt[(c4 * 4 + 0) * 64 + row] = v.x;
        swt[(c4 * 4 + 1) * 64 + row] = v.y;
        swt[(c4 * 4 + 2) * 64 + row] = v.z;
        swt[(c4 * 4 + 3) * 64 + row] = v.w;
      }
      __syncthreads();

      float pd[8][4], pf[8][4];
#pragma unroll
      for (int i = 0; i < 8; i++)
#pragma unroll
        for (int j = 0; j < 4; j++) { pd[i][j] = 0.f; pf[i][j] = 0.f; }

#pragma unroll
      for (int c = 0; c < 20; c++) {
        float4 qv[8];
#pragma unroll
        for (int i = 0; i < 8; i++)
          qv[i] = *(const float4*)(sq + (qg * 8 + i) * QST + c * 4);
#pragma unroll
        for (int k = 0; k < 4; k++) {
          const float4 wvk = *(const float4*)(swt + (c * 4 + k) * 64 + wg * 4);
          if (c < 4) {
#pragma unroll
            for (int i = 0; i < 8; i++) {
              const float qik = ((const float*)&qv[i])[k];
              pd[i][0] = fmaf(qik, wvk.x, pd[i][0]);
              pd[i][1] = fmaf(qik, wvk.y, pd[i][1]);
              pd[i][2] = fmaf(qik, wvk.z, pd[i][2]);
              pd[i][3] = fmaf(qik, wvk.w, pd[i][3]);
            }
          } else {
#pragma unroll
            for (int i = 0; i < 8; i++) {
              const float qik = ((const float*)&qv[i])[k];
              pf[i][0] = fmaf(qik, wvk.x, pf[i][0]);
              pf[i][1] = fmaf(qik, wvk.y, pf[i][1]);
              pf[i][2] = fmaf(qik, wvk.z, pf[i][2]);
              pf[i][3] = fmaf(qik, wvk.w, pf[i][3]);
            }
          }
        }
      }
#pragma unroll
      for (int i = 0; i < 8; i++)
#pragma unroll
        for (int j = 0; j < 4; j++) acc[i][j] = fmaf(pd[i][j], pf[i][j], acc[i][j]);
      __syncthreads();  // before next head overwrites LDS
    }

    // reduce over w: sum 4 cols, then across wg lanes (16-lane groups)
#pragma unroll
    for (int i = 0; i < 8; i++) {
      float r = acc[i][0] + acc[i][1] + acc[i][2] + acc[i][3];
      r += __shfl_xor(r, 1, 64);
      r += __shfl_xor(r, 2, 64);
      r += __shfl_xor(r, 4, 64);
      r += __shfl_xor(r, 8, 64);
      if (wg == 0) negparts[wb * B_Q + q0 + qg * 8 + i] = r;
    }
  } else {
    // ---------------- pos path ----------------
    const int g = (blockIdx.x - 256) * 64 + (tid >> 2);
    const int h = tid & 3;
    const float* q = qcomp + (size_t)(g >> 3) * CROW;
    const float* w = wcomp + (size_t)g * CROW;
    float pd = 0.f, pf = 0.f;
#pragma unroll
    for (int c = 0; c < 4; c++) {
      const float4 qv = *(const float4*)(q + h * 16 + c * 4);
      const float4 wv = *(const float4*)(w + h * 16 + c * 4);
      pd += qv.x * wv.x + qv.y * wv.y + qv.z * wv.z + qv.w * wv.w;
    }
#pragma unroll
    for (int r = 0; r < 2; r++)
#pragma unroll
      for (int c = 0; c < 8; c++) {
        const float4 qv = *(const float4*)(q + 64 + r * 128 + h * 32 + c * 4);
        const float4 wv = *(const float4*)(w + 64 + r * 128 + h * 32 + c * 4);
        pf += qv.x * wv.x + qv.y * wv.y + qv.z * wv.z + qv.w * wv.w;
      }
    float sc = pd * pf;
    sc += __shfl_xor(sc, 1, 64);
    sc += __shfl_xor(sc, 2, 64);
    if (h == 0) pos[g] = sc;
  }
}

__global__ __launch_bounds__(1024) void k_loss(const float* __restrict__ pos,
                                               const float* __restrict__ negparts,
                                               const float* __restrict__ lmask,
                                               float* __restrict__ out) {
  const int b = threadIdx.x;
  float lp[8];
  float possum = 0.f;
#pragma unroll
  for (int k = 0; k < 8; k++) { lp[k] = pos[b * 8 + k]; possum += lp[k]; }
  float negsum = 0.f;
#pragma unroll 8
  for (int c = 0; c < NWT; c++) negsum += negparts[c * B_Q + b];
  const float Z = possum + negsum + 2.056e-5f;  // + 2056 * 1e-8
  const float logZ = logf(Z);
  float local = 0.f, lsum = 0.f;
#pragma unroll
  for (int k = 0; k < 8; k++) {
    const float lm = lmask[b * 8 + k];
    local += lm * (logf(lp[k] + 1e-8f) - logZ);
    lsum += lm;
  }
  local = wave_sum(local);
  lsum = wave_sum(lsum);
  __shared__ float r1[16], r2[16];
  const int wid = b >> 6;
  if ((b & 63) == 0) { r1[wid] = local; r2[wid] = lsum; }
  __syncthreads();
  if (b == 0) {
    float t1 = 0.f, t2 = 0.f;
    for (int wv = 0; wv < 16; wv++) { t1 += r1[wv]; t2 += r2[wv]; }
    out[0] = -t1 / (t2 + 1e-6f);
  }
}

extern "C" void kernel_launch(void* const* d_in, const int* in_sizes, int n_in,
                              void* d_out, int out_size, void* d_ws, size_t ws_size,
                              hipStream_t stream) {
  const int* indices  = (const int*)d_in[0];
  const float* mask   = (const float*)d_in[1];
  const int* labels   = (const int*)d_in[2];
  const float* lmask  = (const float*)d_in[3];
  const int* negidx   = (const int*)d_in[4];
  const float* embed  = (const float*)d_in[5];
  const float* kern   = (const float*)d_in[6];
  const float* omega  = (const float*)d_in[7];
  const float* anchors= (const float*)d_in[8];
  float* out = (float*)d_out;

  float* ws = (float*)d_ws;
  float* anchT    = ws;                            // 1024
  float* qcomp    = anchT + 1024;                  // 1024*320
  float* wcomp    = qcomp + (size_t)B_Q * CROW;    // 10240*320
  float* pos      = wcomp + (size_t)W_ROWS * CROW; // 8192
  float* negparts = pos + LBL_ROWS;                // 32*1024
  int*   jidx     = (int*)(negparts + NWT * B_Q);  // 10240
  int*   sorted   = jidx + W_ROWS;                 // 10240

  k_setup<<<2, 256, 0, stream>>>(anchors, labels, negidx, anchT, jidx, sorted);
  k_feat<<<NWB + B_Q, 256, 0, stream>>>(indices, mask, embed, kern, anchT, omega,
                                        jidx, sorted, qcomp, wcomp);
  k_score<<<256 + 128, 256, 0, stream>>>(qcomp, wcomp, negparts, pos);
  k_loss<<<1, 1024, 0, stream>>>(pos, negparts, lmask, out);
}